// Round 11
// baseline (104.242 us; speedup 1.0000x reference)
//
#include <hip/hip_runtime.h>
#include <float.h>

// CropRoi, LDS-staged, channel-interleaved float4 LDS, 3x3x3 phase 2.
// (v8 structure — best so far — plus two scheduling fixes:)
//  * NTHREADS 256->384: 24 waves/CU (was 16) for latency hiding; phase 2 is
//    a single round (343 <= 384) instead of 256+87 two-round.
//  * grid swapped to (n, channel-group): consecutive blocks share the same
//    4-channel planes -> better L2 locality for staging.
//
// Domain: sides in [8,48] => crop length L <= 13 => adaptive segment length
// 1..3; elements {a0, min(a0+1,a1-1), a1-1} cover all cases (duplicates
// idempotent under max). LDS 2197*16B = 35.2 KB -> 4 blocks/CU.

#define NTHREADS 384
#define NCH 4
#define MAXL 13
#define MAXV (MAXL * MAXL * MAXL)  // 2197
#define BATCH 6                     // 6*384 = 2304 >= 2197

__global__ __launch_bounds__(NTHREADS) void crop_roi_v10(
        const float* __restrict__ f,
        const float* __restrict__ props,
        float* __restrict__ out,
        int C) {
    __shared__ float4 s4[MAXV];  // 35.2 KB, channel-interleaved
    const int n = blockIdx.x;          // proposal (fast dim -> L2 locality)
    const int cbase = blockIdx.y * NCH;
    const int tid = threadIdx.x;

    const float* p = props + (size_t)n * 8;
    const int b = (int)p[0];

    // Bounds: float math matches JAX f32 exactly (exact *0.5, *0.25).
    int d0 = (int)floorf((p[2] - p[5] * 0.5f) * 0.25f);
    int d1 = (int)ceilf ((p[2] + p[5] * 0.5f) * 0.25f);
    int h0 = (int)floorf((p[3] - p[6] * 0.5f) * 0.25f);
    int h1 = (int)ceilf ((p[3] + p[6] * 0.5f) * 0.25f);
    int w0 = (int)floorf((p[4] - p[7] * 0.5f) * 0.25f);
    int w1 = (int)ceilf ((p[4] + p[7] * 0.5f) * 0.25f);
    d0 = max(d0, 0); d1 = min(d1, 32);
    h0 = max(h0, 0); h1 = min(h1, 32);
    w0 = max(w0, 0); w1 = min(w1, 32);
    const int Ld = d1 - d0, Lh = h1 - h0, Lw = w1 - w0;

    const float* base0 = f + (((size_t)b * C + cbase) << 15);  // 32^3
    const int nch = min(NCH, C - cbase);

    size_t choff[NCH];
#pragma unroll
    for (int cs = 0; cs < NCH; ++cs)
        choff[cs] = (size_t)min(cs, nch - 1) << 15;

    if (Ld >= 1 && Ld <= MAXL && Lh >= 1 && Lh <= MAXL && Lw >= 1 && Lw <= MAXL) {
        const int D1 = Lh * Lw;   // <= 169
        const int V  = Ld * D1;   // <= 2197 (block-uniform)
        // magic reciprocals: exact floor-div for e < 2^12 (M = 2^32/D + 1)
        const unsigned Mdh = (D1 > 1) ? (unsigned)(0x100000000ULL / (unsigned)D1) + 1u : 0u;
        const unsigned Mw  = (Lw > 1) ? (unsigned)(0x100000000ULL / (unsigned)Lw) + 1u : 0u;

        // Phase 1: guarded batched staging (single pass, BATCH*384 >= 2197).
        float rv[BATCH][NCH];
        int   ec[BATCH];
#pragma unroll
        for (int u = 0; u < BATCH; ++u) {
            const int e = tid + u * NTHREADS;
            if (e < V) {  // V block-uniform -> divergent only at boundary wave
                unsigned d = (D1 > 1) ? __umulhi((unsigned)e, Mdh) : (unsigned)e;
                unsigned r = (unsigned)e - d * (unsigned)D1;
                unsigned h = (Lw > 1) ? __umulhi(r, Mw) : r;
                unsigned w = r - h * (unsigned)Lw;
                const int g = ((((d0 + (int)d) << 5) + (h0 + (int)h)) << 5)
                              + w0 + (int)w;
                ec[u] = e;
#pragma unroll
                for (int cs = 0; cs < NCH; ++cs)
                    rv[u][cs] = base0[choff[cs] + g];
            }
        }
#pragma unroll
        for (int u = 0; u < BATCH; ++u) {
            if (tid + u * NTHREADS < V) {
                s4[ec[u]] = make_float4(rv[u][0], rv[u][1], rv[u][2], rv[u][3]);
            }
        }
        __syncthreads();

        // Phase 2: 3x3x3 clamped window, one ds_read_b128 per index,
        // single round (343 <= NTHREADS).
        if (tid < 343) {
            const int o = tid;
            const int i = o / 49;
            const int j = (o / 7) % 7;
            const int k = o % 7;
            const int a0 = (i * Ld) / 7,  a1 = ((i + 1) * Ld + 6) / 7;
            const int b0 = (j * Lh) / 7,  b1 = ((j + 1) * Lh + 6) / 7;
            const int g0 = (k * Lw) / 7,  g1 = ((k + 1) * Lw + 6) / 7;
            // segment elements: {a0, min(a0+1, a1-1), a1-1} (len 1..3)
            const int dd[3] = { a0, min(a0 + 1, a1 - 1), a1 - 1 };
            const int hh[3] = { b0, min(b0 + 1, b1 - 1), b1 - 1 };
            const int ww[3] = { g0, min(g0 + 1, g1 - 1), g1 - 1 };
            float m0 = -FLT_MAX, m1 = -FLT_MAX, m2 = -FLT_MAX, m3 = -FLT_MAX;
#pragma unroll
            for (int x = 0; x < 3; ++x) {
#pragma unroll
                for (int y = 0; y < 3; ++y) {
                    const int rowb = (dd[x] * Lh + hh[y]) * Lw;
#pragma unroll
                    for (int z = 0; z < 3; ++z) {
                        const float4 v = s4[rowb + ww[z]];
                        m0 = fmaxf(m0, v.x);
                        m1 = fmaxf(m1, v.y);
                        m2 = fmaxf(m2, v.z);
                        m3 = fmaxf(m3, v.w);
                    }
                }
            }
            const float mm[NCH] = { m0, m1, m2, m3 };
            for (int cs = 0; cs < nch; ++cs)
                out[((size_t)n * C + cbase + cs) * 343 + o] = mm[cs];
        }
    } else {
        // Robust fallback (not taken for harness inputs): direct from global.
        for (int o = tid; o < 343; o += NTHREADS) {
            const int i = o / 49, j = (o / 7) % 7, k = o % 7;
            const int ds = d0 + (i * Ld) / 7, de = d0 + ((i + 1) * Ld + 6) / 7;
            const int hs = h0 + (j * Lh) / 7, he = h0 + ((j + 1) * Lh + 6) / 7;
            const int ws = w0 + (k * Lw) / 7, we = w0 + ((k + 1) * Lw + 6) / 7;
            for (int cs = 0; cs < nch; ++cs) {
                float m = -FLT_MAX;
                const float* basec = base0 + ((size_t)cs << 15);
                for (int d = ds; d < de; ++d)
                    for (int h = hs; h < he; ++h) {
                        const float* row = basec + (d << 10) + (h << 5);
                        for (int w = ws; w < we; ++w) m = fmaxf(m, row[w]);
                    }
                out[((size_t)n * C + cbase + cs) * 343 + o] = m;
            }
        }
    }
}

extern "C" void kernel_launch(void* const* d_in, const int* in_sizes, int n_in,
                              void* d_out, int out_size, void* d_ws, size_t ws_size,
                              hipStream_t stream) {
    const float* f = (const float*)d_in[0];
    const float* props = (const float*)d_in[2];

    int N = in_sizes[2] / 8;       // proposals are (N, 8)
    int C = out_size / (N * 343);  // outputs are (N, C, 7, 7, 7)

    dim3 block(NTHREADS);
    dim3 grid(N, (C + NCH - 1) / NCH);   // n fast -> channel-plane L2 reuse
    crop_roi_v10<<<grid, block, 0, stream>>>(f, props, (float*)d_out, C);
}

// Round 12
// 101.181 us; speedup vs baseline: 1.0302x; 1.0302x over previous
//
#include <hip/hip_runtime.h>
#include <float.h>

// CropRoi, LDS-staged, channel-interleaved float4, separable pool in LDS.
// (v8 base — measured best — with ONE change: separable phase 2.)
//
// Phase 1: stage crop (V = Ld*Lh*Lw <= 2197 float4s, channel-interleaved)
//          with guarded 9-deep batched global dword loads (coalesced).
// Phase 2a (fast path, V + Ld*Lh*7 <= 2197 — holds for avg crops 512+448):
//          w-pool into t1[d][h][k] stored in the unused TAIL of s4 at
//          offset V: 3 ds_read_b128 + 1 ds_write_b128 per item.
//          t1 linear index (d*Lh+h)*7+k == item id e, and row base in s4
//          is q*Lw with q = e/7 = d*Lh+h. Read/write regions disjoint.
// Phase 2b: 9 ds_read_b128 per output (3 d x 3 h, k pre-pooled) — was 27.
// Fallback when V+Vt > 2197 (near-max crops) or L > 13: v8's 27-read path /
// direct-global path. All paths exact.
//
// Domain: sides in [8,48] => L <= 13 => segment length 1..3; elements
// {a0, min(a0+1,a1-1), a1-1} cover all cases (dups idempotent under max).
// LDS 2197*16 B = 35.2 KB -> 4 blocks/CU.

#define NTHREADS 256
#define NCH 4
#define MAXL 13
#define MAXV (MAXL * MAXL * MAXL)  // 2197
#define BATCH 9

__global__ __launch_bounds__(NTHREADS, 4) void crop_roi_v11(
        const float* __restrict__ f,
        const float* __restrict__ props,
        float* __restrict__ out,
        int C) {
    __shared__ float4 s4[MAXV];  // 35.2 KB
    const int cbase = blockIdx.x * NCH;
    const int n = blockIdx.y;
    const int tid = threadIdx.x;

    const float* p = props + (size_t)n * 8;
    const int b = (int)p[0];

    // Bounds: float math matches JAX f32 exactly (exact *0.5, *0.25).
    int d0 = (int)floorf((p[2] - p[5] * 0.5f) * 0.25f);
    int d1 = (int)ceilf ((p[2] + p[5] * 0.5f) * 0.25f);
    int h0 = (int)floorf((p[3] - p[6] * 0.5f) * 0.25f);
    int h1 = (int)ceilf ((p[3] + p[6] * 0.5f) * 0.25f);
    int w0 = (int)floorf((p[4] - p[7] * 0.5f) * 0.25f);
    int w1 = (int)ceilf ((p[4] + p[7] * 0.5f) * 0.25f);
    d0 = max(d0, 0); d1 = min(d1, 32);
    h0 = max(h0, 0); h1 = min(h1, 32);
    w0 = max(w0, 0); w1 = min(w1, 32);
    const int Ld = d1 - d0, Lh = h1 - h0, Lw = w1 - w0;

    const float* base0 = f + (((size_t)b * C + cbase) << 15);  // 32^3
    const int nch = min(NCH, C - cbase);

    size_t choff[NCH];
#pragma unroll
    for (int cs = 0; cs < NCH; ++cs)
        choff[cs] = (size_t)min(cs, nch - 1) << 15;

    if (Ld >= 1 && Ld <= MAXL && Lh >= 1 && Lh <= MAXL && Lw >= 1 && Lw <= MAXL) {
        const int D1 = Lh * Lw;      // <= 169
        const int V  = Ld * D1;      // <= 2197 (block-uniform)
        const int Vt = Ld * Lh * 7;  // w-pooled items (block-uniform)
        // magic reciprocals: exact floor-div for e < 2^12 (M = 2^32/D + 1)
        const unsigned Mdh = (D1 > 1) ? (unsigned)(0x100000000ULL / (unsigned)D1) + 1u : 0u;
        const unsigned Mw  = (Lw > 1) ? (unsigned)(0x100000000ULL / (unsigned)Lw) + 1u : 0u;
        const unsigned Mh  = (Lh > 1) ? (unsigned)(0x100000000ULL / (unsigned)Lh) + 1u : 0u;

        // Phase 1: guarded batched staging (single pass, BATCH*256 >= 2197).
        float rv[BATCH][NCH];
        int   ec[BATCH];
#pragma unroll
        for (int u = 0; u < BATCH; ++u) {
            const int e = tid + u * NTHREADS;
            if (e < V) {  // V block-uniform -> divergent only at boundary wave
                unsigned d = (D1 > 1) ? __umulhi((unsigned)e, Mdh) : (unsigned)e;
                unsigned r = (unsigned)e - d * (unsigned)D1;
                unsigned h = (Lw > 1) ? __umulhi(r, Mw) : r;
                unsigned w = r - h * (unsigned)Lw;
                const int g = ((((d0 + (int)d) << 5) + (h0 + (int)h)) << 5)
                              + w0 + (int)w;
                ec[u] = e;
#pragma unroll
                for (int cs = 0; cs < NCH; ++cs)
                    rv[u][cs] = base0[choff[cs] + g];
            }
        }
#pragma unroll
        for (int u = 0; u < BATCH; ++u) {
            if (tid + u * NTHREADS < V) {
                s4[ec[u]] = make_float4(rv[u][0], rv[u][1], rv[u][2], rv[u][3]);
            }
        }
        __syncthreads();

        if (V + Vt <= MAXV) {
            // ---- Separable fast path (typical: 512 + 448 << 2197) ----
            // Phase 2a: w-pool -> t1 at s4+V. t1[(d*Lh+h)*7+k] == t1[e].
            float4* t1 = s4 + V;
            for (int e = tid; e < Vt; e += NTHREADS) {
                const int k = e % 7;      // const-divisor magic (compiler)
                const int q = e / 7;      // q = d*Lh + h < 169
                const int g0 = (k * Lw) / 7;
                const int g1 = ((k + 1) * Lw + 6) / 7;
                const int rowb = q * Lw;
                const int wA = rowb + g0;
                const int wB = rowb + min(g0 + 1, g1 - 1);
                const int wC = rowb + g1 - 1;
                const float4 vA = s4[wA];
                const float4 vB = s4[wB];
                const float4 vC = s4[wC];
                float4 mx;
                mx.x = fmaxf(fmaxf(vA.x, vB.x), vC.x);
                mx.y = fmaxf(fmaxf(vA.y, vB.y), vC.y);
                mx.z = fmaxf(fmaxf(vA.z, vB.z), vC.z);
                mx.w = fmaxf(fmaxf(vA.w, vB.w), vC.w);
                t1[e] = mx;
            }
            __syncthreads();

            // Phase 2b: pool d,h — 9 ds_read_b128 per output.
            for (int o = tid; o < 343; o += NTHREADS) {
                const int i = o / 49;
                const int j = (o / 7) % 7;
                const int k = o % 7;
                const int a0 = (i * Ld) / 7,  a1 = ((i + 1) * Ld + 6) / 7;
                const int b0 = (j * Lh) / 7,  b1 = ((j + 1) * Lh + 6) / 7;
                const int dd[3] = { a0, min(a0 + 1, a1 - 1), a1 - 1 };
                const int hh[3] = { b0, min(b0 + 1, b1 - 1), b1 - 1 };
                float m0 = -FLT_MAX, m1 = -FLT_MAX, m2 = -FLT_MAX, m3 = -FLT_MAX;
#pragma unroll
                for (int x = 0; x < 3; ++x) {
#pragma unroll
                    for (int y = 0; y < 3; ++y) {
                        const float4 v = t1[(dd[x] * Lh + hh[y]) * 7 + k];
                        m0 = fmaxf(m0, v.x);
                        m1 = fmaxf(m1, v.y);
                        m2 = fmaxf(m2, v.z);
                        m3 = fmaxf(m3, v.w);
                    }
                }
                const float mm[NCH] = { m0, m1, m2, m3 };
                for (int cs = 0; cs < nch; ++cs)
                    out[((size_t)n * C + cbase + cs) * 343 + o] = mm[cs];
            }
        } else {
            // ---- v8 path (near-max crops): 27-read 3x3x3 window ----
            for (int o = tid; o < 343; o += NTHREADS) {
                const int i = o / 49;
                const int j = (o / 7) % 7;
                const int k = o % 7;
                const int a0 = (i * Ld) / 7,  a1 = ((i + 1) * Ld + 6) / 7;
                const int b0 = (j * Lh) / 7,  b1 = ((j + 1) * Lh + 6) / 7;
                const int g0 = (k * Lw) / 7,  g1 = ((k + 1) * Lw + 6) / 7;
                const int dd[3] = { a0, min(a0 + 1, a1 - 1), a1 - 1 };
                const int hh[3] = { b0, min(b0 + 1, b1 - 1), b1 - 1 };
                const int ww[3] = { g0, min(g0 + 1, g1 - 1), g1 - 1 };
                float m0 = -FLT_MAX, m1 = -FLT_MAX, m2 = -FLT_MAX, m3 = -FLT_MAX;
#pragma unroll
                for (int x = 0; x < 3; ++x) {
#pragma unroll
                    for (int y = 0; y < 3; ++y) {
                        const int rowb = (dd[x] * Lh + hh[y]) * Lw;
#pragma unroll
                        for (int z = 0; z < 3; ++z) {
                            const float4 v = s4[rowb + ww[z]];
                            m0 = fmaxf(m0, v.x);
                            m1 = fmaxf(m1, v.y);
                            m2 = fmaxf(m2, v.z);
                            m3 = fmaxf(m3, v.w);
                        }
                    }
                }
                const float mm[NCH] = { m0, m1, m2, m3 };
                for (int cs = 0; cs < nch; ++cs)
                    out[((size_t)n * C + cbase + cs) * 343 + o] = mm[cs];
            }
        }
    } else {
        // Robust fallback (not taken for harness inputs): direct from global.
        for (int o = tid; o < 343; o += NTHREADS) {
            const int i = o / 49, j = (o / 7) % 7, k = o % 7;
            const int ds = d0 + (i * Ld) / 7, de = d0 + ((i + 1) * Ld + 6) / 7;
            const int hs = h0 + (j * Lh) / 7, he = h0 + ((j + 1) * Lh + 6) / 7;
            const int ws = w0 + (k * Lw) / 7, we = w0 + ((k + 1) * Lw + 6) / 7;
            for (int cs = 0; cs < nch; ++cs) {
                float m = -FLT_MAX;
                const float* basec = base0 + ((size_t)cs << 15);
                for (int d = ds; d < de; ++d)
                    for (int h = hs; h < he; ++h) {
                        const float* row = basec + (d << 10) + (h << 5);
                        for (int w = ws; w < we; ++w) m = fmaxf(m, row[w]);
                    }
                out[((size_t)n * C + cbase + cs) * 343 + o] = m;
            }
        }
    }
}

extern "C" void kernel_launch(void* const* d_in, const int* in_sizes, int n_in,
                              void* d_out, int out_size, void* d_ws, size_t ws_size,
                              hipStream_t stream) {
    const float* f = (const float*)d_in[0];
    const float* props = (const float*)d_in[2];

    int N = in_sizes[2] / 8;       // proposals are (N, 8)
    int C = out_size / (N * 343);  // outputs are (N, C, 7, 7, 7)

    dim3 block(NTHREADS);
    dim3 grid((C + NCH - 1) / NCH, N);
    crop_roi_v11<<<grid, block, 0, stream>>>(f, props, (float*)d_out, C);
}

// Round 13
// 100.668 us; speedup vs baseline: 1.0355x; 1.0051x over previous
//
#include <hip/hip_runtime.h>
#include <float.h>

// CropRoi — FINAL (revert to measured-best v8, bench 100.8 µs).
//
// Structure: LDS-staged crop, channel-interleaved float4 LDS, fully-unrolled
// 3x3x3 clamped-window phase 2.
//   Phase 1: guarded 9-deep batched coalesced global dword loads (4 ch),
//            one ds_write_b128 per element. MLP ~32 loads in flight.
//   Phase 2: 27 ds_read_b128 per output (4 channels per read), branch-free.
//
// Domain: sides in [8,48] => crop length L <= 13 => adaptive segment length
// 1..3; elements {a0, min(a0+1,a1-1), a1-1} cover all cases (duplicates
// idempotent under max). LDS 2197*16B = 35.2 KB -> 4 blocks/CU.
//
// Plateau evidence (R9-R12): phase-2 issue-count, occupancy, and grid-order
// variants all land within ±3.4 µs of this config; remaining kernel time
// (~15 µs vs ~2.8 µs traffic roofline) is cold-cache first-touch latency
// (harness flushes L2/L3 via 268 MB poison fills every replay) + launch/
// drain — not addressable at instruction level.

#define NTHREADS 256
#define NCH 4
#define MAXL 13
#define MAXV (MAXL * MAXL * MAXL)  // 2197
#define BATCH 9

__global__ __launch_bounds__(NTHREADS, 4) void crop_roi_v8(
        const float* __restrict__ f,
        const float* __restrict__ props,
        float* __restrict__ out,
        int C) {
    __shared__ float4 s4[MAXV];  // 35.2 KB, channel-interleaved
    const int cbase = blockIdx.x * NCH;
    const int n = blockIdx.y;
    const int tid = threadIdx.x;

    const float* p = props + (size_t)n * 8;
    const int b = (int)p[0];

    // Bounds: float math matches JAX f32 exactly (exact *0.5, *0.25).
    int d0 = (int)floorf((p[2] - p[5] * 0.5f) * 0.25f);
    int d1 = (int)ceilf ((p[2] + p[5] * 0.5f) * 0.25f);
    int h0 = (int)floorf((p[3] - p[6] * 0.5f) * 0.25f);
    int h1 = (int)ceilf ((p[3] + p[6] * 0.5f) * 0.25f);
    int w0 = (int)floorf((p[4] - p[7] * 0.5f) * 0.25f);
    int w1 = (int)ceilf ((p[4] + p[7] * 0.5f) * 0.25f);
    d0 = max(d0, 0); d1 = min(d1, 32);
    h0 = max(h0, 0); h1 = min(h1, 32);
    w0 = max(w0, 0); w1 = min(w1, 32);
    const int Ld = d1 - d0, Lh = h1 - h0, Lw = w1 - w0;

    const float* base0 = f + (((size_t)b * C + cbase) << 15);  // 32^3
    const int nch = min(NCH, C - cbase);

    size_t choff[NCH];
#pragma unroll
    for (int cs = 0; cs < NCH; ++cs)
        choff[cs] = (size_t)min(cs, nch - 1) << 15;

    if (Ld >= 1 && Ld <= MAXL && Lh >= 1 && Lh <= MAXL && Lw >= 1 && Lw <= MAXL) {
        const int D1 = Lh * Lw;   // <= 169
        const int V  = Ld * D1;   // <= 2197 (block-uniform)
        // magic reciprocals: exact floor-div for e < 2^12 (M = 2^32/D + 1)
        const unsigned Mdh = (D1 > 1) ? (unsigned)(0x100000000ULL / (unsigned)D1) + 1u : 0u;
        const unsigned Mw  = (Lw > 1) ? (unsigned)(0x100000000ULL / (unsigned)Lw) + 1u : 0u;

        // Phase 1: guarded batched staging (single pass, BATCH*256 >= 2197).
        float rv[BATCH][NCH];
        int   ec[BATCH];
#pragma unroll
        for (int u = 0; u < BATCH; ++u) {
            const int e = tid + u * NTHREADS;
            if (e < V) {  // V block-uniform -> divergent only at boundary wave
                unsigned d = (D1 > 1) ? __umulhi((unsigned)e, Mdh) : (unsigned)e;
                unsigned r = (unsigned)e - d * (unsigned)D1;
                unsigned h = (Lw > 1) ? __umulhi(r, Mw) : r;
                unsigned w = r - h * (unsigned)Lw;
                const int g = ((((d0 + (int)d) << 5) + (h0 + (int)h)) << 5)
                              + w0 + (int)w;
                ec[u] = e;
#pragma unroll
                for (int cs = 0; cs < NCH; ++cs)
                    rv[u][cs] = base0[choff[cs] + g];
            }
        }
#pragma unroll
        for (int u = 0; u < BATCH; ++u) {
            if (tid + u * NTHREADS < V) {
                s4[ec[u]] = make_float4(rv[u][0], rv[u][1], rv[u][2], rv[u][3]);
            }
        }
        __syncthreads();

        // Phase 2: 3x3x3 clamped window, one ds_read_b128 per index.
        for (int o = tid; o < 343; o += NTHREADS) {
            const int i = o / 49;
            const int j = (o / 7) % 7;
            const int k = o % 7;
            const int a0 = (i * Ld) / 7,  a1 = ((i + 1) * Ld + 6) / 7;
            const int b0 = (j * Lh) / 7,  b1 = ((j + 1) * Lh + 6) / 7;
            const int g0 = (k * Lw) / 7,  g1 = ((k + 1) * Lw + 6) / 7;
            // segment elements: {a0, min(a0+1, a1-1), a1-1} (len 1..3)
            const int dd[3] = { a0, min(a0 + 1, a1 - 1), a1 - 1 };
            const int hh[3] = { b0, min(b0 + 1, b1 - 1), b1 - 1 };
            const int ww[3] = { g0, min(g0 + 1, g1 - 1), g1 - 1 };
            float m0 = -FLT_MAX, m1 = -FLT_MAX, m2 = -FLT_MAX, m3 = -FLT_MAX;
#pragma unroll
            for (int x = 0; x < 3; ++x) {
#pragma unroll
                for (int y = 0; y < 3; ++y) {
                    const int rowb = (dd[x] * Lh + hh[y]) * Lw;
#pragma unroll
                    for (int z = 0; z < 3; ++z) {
                        const float4 v = s4[rowb + ww[z]];
                        m0 = fmaxf(m0, v.x);
                        m1 = fmaxf(m1, v.y);
                        m2 = fmaxf(m2, v.z);
                        m3 = fmaxf(m3, v.w);
                    }
                }
            }
            const float mm[NCH] = { m0, m1, m2, m3 };
            for (int cs = 0; cs < nch; ++cs)
                out[((size_t)n * C + cbase + cs) * 343 + o] = mm[cs];
        }
    } else {
        // Robust fallback (not taken for harness inputs): direct from global.
        for (int o = tid; o < 343; o += NTHREADS) {
            const int i = o / 49, j = (o / 7) % 7, k = o % 7;
            const int ds = d0 + (i * Ld) / 7, de = d0 + ((i + 1) * Ld + 6) / 7;
            const int hs = h0 + (j * Lh) / 7, he = h0 + ((j + 1) * Lh + 6) / 7;
            const int ws = w0 + (k * Lw) / 7, we = w0 + ((k + 1) * Lw + 6) / 7;
            for (int cs = 0; cs < nch; ++cs) {
                float m = -FLT_MAX;
                const float* basec = base0 + ((size_t)cs << 15);
                for (int d = ds; d < de; ++d)
                    for (int h = hs; h < he; ++h) {
                        const float* row = basec + (d << 10) + (h << 5);
                        for (int w = ws; w < we; ++w) m = fmaxf(m, row[w]);
                    }
                out[((size_t)n * C + cbase + cs) * 343 + o] = m;
            }
        }
    }
}

extern "C" void kernel_launch(void* const* d_in, const int* in_sizes, int n_in,
                              void* d_out, int out_size, void* d_ws, size_t ws_size,
                              hipStream_t stream) {
    const float* f = (const float*)d_in[0];
    const float* props = (const float*)d_in[2];

    int N = in_sizes[2] / 8;       // proposals are (N, 8)
    int C = out_size / (N * 343);  // outputs are (N, C, 7, 7, 7)

    dim3 block(NTHREADS);
    dim3 grid((C + NCH - 1) / NCH, N);
    crop_roi_v8<<<grid, block, 0, stream>>>(f, props, (float*)d_out, C);
}